// Round 4
// baseline (879.514 us; speedup 1.0000x reference)
//
#include <hip/hip_runtime.h>

// Vanilla tanh RNN. B=64, T=2048, I=64, H=128, fp32.
//   xw[b,t,h] = sum_i x[b,t,i]*W[h,i] + b_ih[h] + b_hh[h]
//   h_t = tanh(xw_t + h_{t-1} @ U^T);  outputs: ys [B,T,H], h_last [B,H]
//
// R8. Post-mortem of R6/R7 (650us scan, VGPR=60): the R=4 U tile (64
// VGPRs) was NOT kept resident — the compiler rematerialized the
// loop-invariant U loads inside the step loop. U is L2-resident (64KB)
// so FETCH didn't move, but ~200cyc L2 latency landed in the serial
// per-step chain: swapped R5's LDS-BW bound (64KB/step) for an
// L2-latency bound at the same ~760 cyc/step. Fix:
//   (a) PIN u[4][4] (and w[4][4] in gemm) via empty asm "+v" touches:
//       values become asm-defined -> remat illegal -> must stay in VGPR
//       (cap is 512 at launch_bounds(256,1); no reason to spill).
//   (b) Prefetch next xw chunk into regs before the 32-step loop (T14):
//       HBM latency hides under the steps instead of stalling Phase A.
//   (c) Drop obuf: output lanes (j>=4) store directly to global
//       (fire-and-forget, 512B/step contiguous per block). Removes the
//       flush phase + 16KB LDS. if/else (not ptr-select) so stores stay
//       ds_write vs global_store, not flat.
// Structure otherwise = R6: scan 256 thr, thread(g=tid>>3,j=tid&7) owns
// U rows 4g..4g+3 x k-slice [16j,16j+16) (16 float4); 4x ds_read_b128
// per step (16KB/step/CU); 8-lane DPP butterfly xor1(0xB1)+xor2(0x4E)+
// half_mirror(0x141); h skew (k>>4)*20+(k&15).
// (R9 = R8 resubmitted verbatim: R8 bench hit GPUAcquisitionTimeout,
//  no measurement was taken.)

#define RNN_B 64
#define RNN_T 2048
#define RNN_I 64
#define RNN_H 128
#define CH    32            // timesteps per staged chunk
#define NCH   (RNN_T / CH)  // 64 chunks

__device__ __forceinline__ float fast_tanh(float x) {
  // tanh(x) = 1 - 2/(e^{2x}+1);  e^{2x} = exp2(x * 2*log2(e))
  float e = __builtin_amdgcn_exp2f(x * 2.885390081777927f);
  return 1.0f - 2.0f * __builtin_amdgcn_rcpf(e + 1.0f);
}

template <int CTRL>
__device__ __forceinline__ float dpp_add(float s) {
  int o = __builtin_amdgcn_mov_dpp(__float_as_int(s), CTRL, 0xF, 0xF, true);
  return s + __int_as_float(o);
}

__device__ __forceinline__ void fma4(float4& a, const float4 u, const float4 h) {
  a.x = fmaf(u.x, h.x, a.x);
  a.y = fmaf(u.y, h.y, a.y);
  a.z = fmaf(u.z, h.z, a.z);
  a.w = fmaf(u.w, h.w, a.w);
}

__device__ __forceinline__ float hsum(const float4 a) {
  return (a.x + a.y) + (a.z + a.w);
}

// Make a loaded value asm-defined: the compiler can no longer rematerialize
// it from memory, so it stays in VGPRs (R6 lesson: VGPR_Count=60 < the 64
// needed for u alone -> per-step L2 reloads on the critical chain).
__device__ __forceinline__ void pin4(float4& v) {
  asm volatile("" : "+v"(v.x), "+v"(v.y), "+v"(v.z), "+v"(v.w));
}

// ---------------------------------------------------------------------------
// Kernel 1: xw = x @ W^T + (b_ih + b_hh).  M=B*T=131072, N=128, K=64.
// 2048 blocks x 256 threads, 64 x-rows/block.
// whalf=wave&1 owns W rows [64*whalf, 64*whalf+64); pair=wave>>1 processes
// x-rows [32*pair, 32*pair+32). lane -> (g2=lane>>2: rows 4g2..4g2+3,
// q2=lane&3: k-slice [16q2,16q2+16)): 16 float4 of W in regs (pinned).
// Quad butterfly -> all 4 lanes hold all 4 row sums; lane keeps row
// 4g2+q2, i.e. global row 64*whalf+lane -> coalesced dword store.
// ---------------------------------------------------------------------------
__global__ __launch_bounds__(256, 2) void rnn_xw_gemm(
    const float* __restrict__ x, const float* __restrict__ W,
    const float* __restrict__ b_ih, const float* __restrict__ b_hh,
    float* __restrict__ xw) {
  const int tid   = threadIdx.x;
  const int wave  = tid >> 6;
  const int lane  = tid & 63;
  const int whalf = wave & 1;
  const int pair  = wave >> 1;
  const int g2    = lane >> 2;
  const int q2    = lane & 3;

  // W tile: rows 64*whalf + 4g2 .. +3, cols [16q2, 16q2+16) -> 16 float4
  float4 w[4][4];
#pragma unroll
  for (int r = 0; r < 4; ++r) {
    const float4* Wr =
        (const float4*)(W + (64 * whalf + 4 * g2 + r) * RNN_I + 16 * q2);
#pragma unroll
    for (int m = 0; m < 4; ++m) { w[r][m] = Wr[m]; pin4(w[r][m]); }
  }
  const int row_own = 64 * whalf + lane;
  const float bias  = b_ih[row_own] + b_hh[row_own];

  // Stage 64 rows of x (64x64 fp32 = 16 KB) into LDS, coalesced.
  __shared__ __align__(16) float4 xs[64 * 16];
  const long rbase = (long)blockIdx.x * 64;
  const float4* xg = (const float4*)(x + rbase * RNN_I);
#pragma unroll
  for (int jj = 0; jj < 4; ++jj) xs[tid + 256 * jj] = xg[tid + 256 * jj];
  __syncthreads();

  for (int i = 0; i < 32; ++i) {
    const int r = 32 * pair + i;
    const float4* xr = xs + r * 16 + q2 * 4;
    float4 a0 = {0,0,0,0}, a1 = {0,0,0,0}, a2 = {0,0,0,0}, a3 = {0,0,0,0};
#pragma unroll
    for (int m = 0; m < 4; ++m) {
      const float4 xv = xr[m];
      fma4(a0, w[0][m], xv);
      fma4(a1, w[1][m], xv);
      fma4(a2, w[2][m], xv);
      fma4(a3, w[3][m], xv);
    }
    float s0 = hsum(a0), s1 = hsum(a1), s2 = hsum(a2), s3 = hsum(a3);
    s0 = dpp_add<0xB1>(s0); s0 = dpp_add<0x4E>(s0);
    s1 = dpp_add<0xB1>(s1); s1 = dpp_add<0x4E>(s1);
    s2 = dpp_add<0xB1>(s2); s2 = dpp_add<0x4E>(s2);
    s3 = dpp_add<0xB1>(s3); s3 = dpp_add<0x4E>(s3);
    const float own = (q2 & 2) ? ((q2 & 1) ? s3 : s2)
                               : ((q2 & 1) ? s1 : s0);
    xw[(rbase + r) * RNN_H + row_own] = own + bias;  // coalesced: row_own==64*whalf+lane
  }
}

// ---------------------------------------------------------------------------
// Kernel 2: sequential scan. 1 block/batch, 256 threads (4 waves, 1/SIMD).
// thread -> (g=tid>>3: U rows 4g..4g+3, j=tid&7: k-slice [16j,16j+16)):
// 16 float4 of U in regs (pinned). 16 KB/step/CU h-broadcast.
// 8-lane butterfly: xor1 + xor2 + half_mirror(0x141) -> full sums in all
// 8 lanes; lane j<4 writes next-h for row 4g+j (skewed slot), lane j>=4
// stores out[b, c*32+tc, 4g+(j&3)] directly to global.
// xw chunks prefetched into regs one chunk ahead (HBM latency hidden
// under the 32 steps). Ping-pong h buffers are compile-time.
// ---------------------------------------------------------------------------
__global__ __launch_bounds__(256, 1) void rnn_scan(
    const float* xw,            // aliases `out` — no __restrict__
    float* out, float* __restrict__ hlast,
    const float* __restrict__ h0, const float* __restrict__ U) {
  const int b     = blockIdx.x;
  const int tid   = threadIdx.x;  // 0..255
  const int g     = tid >> 3;     // 0..31
  const int j     = tid & 7;      // k-slice
  const int r_own = 4 * g + (j & 3);

  __shared__ __align__(16) float hbuf0[8 * 20];     // skewed h state
  __shared__ __align__(16) float hbuf1[8 * 20];
  __shared__ __align__(16) float xbuf[CH * RNN_H];  // 16 KB

  // U tile: rows 4g..4g+3, cols [16j, 16j+16) -> 16 float4 (pinned)
  float4 u[4][4];
#pragma unroll
  for (int r = 0; r < 4; ++r) {
    const float4* Ur = (const float4*)(U + (4 * g + r) * RNN_H + 16 * j);
#pragma unroll
    for (int m = 0; m < 4; ++m) { u[r][m] = Ur[m]; pin4(u[r][m]); }
  }

  if (tid < RNN_H)
    hbuf0[(tid >> 4) * 20 + (tid & 15)] = h0[b * RNN_H + tid];

  const int hoff = (r_own >> 4) * 20 + (r_own & 15);  // skewed write slot
  const long base   = (long)b * RNN_T * RNN_H;
  const float4* xw4 = (const float4*)(xw + base);
  float* outp       = out + base;
  float4* xb4       = (float4*)xbuf;

  // Prologue: prefetch chunk 0 into regs (4 float4/thread).
  float4 p0 = xw4[tid], p1 = xw4[tid + 256],
         p2 = xw4[tid + 512], p3 = xw4[tid + 768];

  auto step = [&](const float* src, float* dst, int tc, float* ob) {
    const float xv = xbuf[tc * RNN_H + r_own];   // no h dependency: issues early
    const float4* hp = (const float4*)(src + 20 * j);
    float4 a0 = {0,0,0,0}, a1 = {0,0,0,0}, a2 = {0,0,0,0}, a3 = {0,0,0,0};
#pragma unroll
    for (int m = 0; m < 4; ++m) {
      const float4 hv = hp[m];
      fma4(a0, u[0][m], hv);
      fma4(a1, u[1][m], hv);
      fma4(a2, u[2][m], hv);
      fma4(a3, u[3][m], hv);
    }
    float s0 = hsum(a0), s1 = hsum(a1), s2 = hsum(a2), s3 = hsum(a3);
    s0 = dpp_add<0xB1>(s0); s0 = dpp_add<0x4E>(s0); s0 = dpp_add<0x141>(s0);
    s1 = dpp_add<0xB1>(s1); s1 = dpp_add<0x4E>(s1); s1 = dpp_add<0x141>(s1);
    s2 = dpp_add<0xB1>(s2); s2 = dpp_add<0x4E>(s2); s2 = dpp_add<0x141>(s2);
    s3 = dpp_add<0xB1>(s3); s3 = dpp_add<0x4E>(s3); s3 = dpp_add<0x141>(s3);
    const float own = (j & 2) ? ((j & 1) ? s3 : s2)
                              : ((j & 1) ? s1 : s0);
    const float val = fast_tanh(own + xv);
    if (j < 4) {
      dst[hoff] = val;                       // ds_write: next h state
    } else {
      ob[tc * RNN_H + r_own] = val;          // global dword, fire-and-forget
    }
    __syncthreads();
  };

  for (int c = 0; c < NCH; ++c) {
    // Phase A: commit prefetched chunk c to LDS; issue prefetch of c+1.
    xb4[tid] = p0; xb4[tid + 256] = p1;
    xb4[tid + 512] = p2; xb4[tid + 768] = p3;
    if (c + 1 < NCH) {
      const float4* nx = xw4 + (long)(c + 1) * 1024;
      p0 = nx[tid]; p1 = nx[tid + 256];
      p2 = nx[tid + 512]; p3 = nx[tid + 768];
    }
    __syncthreads();

    // Phase B: 32 steps; h round-trips LDS, outputs go straight to global.
    float* ob = outp + (long)c * CH * RNN_H;
    for (int tc = 0; tc < CH; tc += 2) {
      step(hbuf0, hbuf1, tc, ob);
      step(hbuf1, hbuf0, tc + 1, ob);
    }
  }

  if (tid < RNN_H)
    hlast[b * RNN_H + tid] = hbuf0[(tid >> 4) * 20 + (tid & 15)];
}

extern "C" void kernel_launch(void* const* d_in, const int* in_sizes, int n_in,
                              void* d_out, int out_size, void* d_ws, size_t ws_size,
                              hipStream_t stream) {
  const float* x    = (const float*)d_in[0];
  const float* h0   = (const float*)d_in[1];
  const float* W    = (const float*)d_in[2];
  const float* U    = (const float*)d_in[3];
  const float* b_ih = (const float*)d_in[4];
  const float* b_hh = (const float*)d_in[5];

  float* out   = (float*)d_out;                           // [B,T,H]
  float* hlast = out + (long)RNN_B * RNN_T * RNN_H;       // [B,H]

  // Stage 1: xw into the output region (read-before-write in scan, per chunk)
  rnn_xw_gemm<<<(RNN_B * RNN_T) / 64, 256, 0, stream>>>(x, W, b_ih, b_hh, out);
  // Stage 2: sequential recurrence, one block per batch element
  rnn_scan<<<RNN_B, 256, 0, stream>>>(out, out, hlast, h0, U);
}

// Round 6
// 800.846 us; speedup vs baseline: 1.0982x; 1.0982x over previous
//
#include <hip/hip_runtime.h>

// Vanilla tanh RNN. B=64, T=2048, I=64, H=128, fp32.
//   xw[b,t,h] = sum_i x[b,t,i]*W[h,i] + b_ih[h] + b_hh[h]
//   h_t = tanh(xw_t + h_{t-1} @ U^T);  outputs: ys [B,T,H], h_last [B,H]
//
// R10. Post-mortem R8 (762us scan, VGPR=64, 893 cyc/step):
//  (1) asm-pin did NOT give residency: pin outlaws remat, not spill — the
//      allocator spilled the 64-float U tile to scratch (L2-resident,
//      invisible in FETCH). ~200cyc L2 reloads still on the serial chain.
//  (2) direct-to-global stores in the step loop cost +131 cyc/step:
//      __syncthreads drains vmcnt(0), so every barrier waited the store
//      ack. NO global ops inside the step loop, ever.
// Fix: tile size with PROVEN residency (R5: 32-float tile @ VGPR=52), and
// 2 waves/SIMD for issue overlap:
//   scan: 512 thr (8 waves, 2/SIMD). thread(g=tid>>3, j=tid&7) owns
//         U rows {2g,2g+1} x cols [16j,16j+16) = 8 float4 (32 VGPR).
//         Per step: 4x ds_read_b128 (32KB/step/CU = 256 pipe cyc,
//         overlapped across waves), 8 fma4, 3-stage all-DPP butterfly
//         xor1(0xB1)+xor2(0x4E)+half_mirror(0x141) over 8 lanes ->
//         all lanes hold both row sums; j<2 writes h'[2g+j] (ds),
//         j==4,5 writes obuf (ds). Outputs flushed obuf->global once
//         per chunk in Phase A.
//   gemm: same shrink: thread(g=tid>>2, q=tid&3) owns W rows {2g,2g+1}
//         x cols [16q,16q+16) (32 VGPR); quad butterfly; q<2 stores
//         row 2g+q (32 contiguous dwords/wave).
//   h skew unchanged: h[k] at float off (k>>4)*20+(k&15); slice bases
//   20j mod 32 = {0,20,8,28,16,4,24,12} all distinct -> conflict-free.
// (R11 = R10 resubmitted verbatim: R10 bench hit GPUAcquisitionTimeout,
//  no measurement was taken.)

#define RNN_B 64
#define RNN_T 2048
#define RNN_I 64
#define RNN_H 128
#define CH    32            // timesteps per staged chunk
#define NCH   (RNN_T / CH)  // 64 chunks

__device__ __forceinline__ float fast_tanh(float x) {
  // tanh(x) = 1 - 2/(e^{2x}+1);  e^{2x} = exp2(x * 2*log2(e))
  float e = __builtin_amdgcn_exp2f(x * 2.885390081777927f);
  return 1.0f - 2.0f * __builtin_amdgcn_rcpf(e + 1.0f);
}

template <int CTRL>
__device__ __forceinline__ float dpp_add(float s) {
  int o = __builtin_amdgcn_mov_dpp(__float_as_int(s), CTRL, 0xF, 0xF, true);
  return s + __int_as_float(o);
}

__device__ __forceinline__ void fma4(float4& a, const float4 u, const float4 h) {
  a.x = fmaf(u.x, h.x, a.x);
  a.y = fmaf(u.y, h.y, a.y);
  a.z = fmaf(u.z, h.z, a.z);
  a.w = fmaf(u.w, h.w, a.w);
}

__device__ __forceinline__ float hsum(const float4 a) {
  return (a.x + a.y) + (a.z + a.w);
}

// Anti-remat touch (kept as cheap insurance; residency now comes from the
// small 8-float4 tile, which R5 proved the allocator keeps).
__device__ __forceinline__ void pin4(float4& v) {
  asm volatile("" : "+v"(v.x), "+v"(v.y), "+v"(v.z), "+v"(v.w));
}

// ---------------------------------------------------------------------------
// Kernel 1: xw = x @ W^T + (b_ih + b_hh).  M=B*T=131072, N=128, K=64.
// 2048 blocks x 256 threads, 64 x-rows/block, 2 blocks/CU.
// thread -> (g=tid>>2: rows 2g,2g+1; q=tid&3: cols [16q,16q+16)):
// 8 float4 of W in regs. Quad butterfly (xor1+xor2) -> all 4 lanes hold
// both row sums; lanes q<2 store row 2g+q -> 32 contiguous dwords/wave.
// ---------------------------------------------------------------------------
__global__ __launch_bounds__(256, 2) void rnn_xw_gemm(
    const float* __restrict__ x, const float* __restrict__ W,
    const float* __restrict__ b_ih, const float* __restrict__ b_hh,
    float* __restrict__ xw) {
  const int tid = threadIdx.x;
  const int g   = tid >> 2;   // 0..63 : rows 2g, 2g+1
  const int q   = tid & 3;    // col slice [16q, 16q+16)

  // W tile: rows 2g,2g+1, cols [16q,16q+16) -> 8 float4 (32 VGPRs)
  float4 w[2][4];
#pragma unroll
  for (int r = 0; r < 2; ++r) {
    const float4* Wr = (const float4*)(W + (2 * g + r) * RNN_I + 16 * q);
#pragma unroll
    for (int m = 0; m < 4; ++m) { w[r][m] = Wr[m]; pin4(w[r][m]); }
  }
  const int row_own = 2 * g + (q & 1);
  const float bias  = b_ih[row_own] + b_hh[row_own];

  // Stage 64 rows of x (64x64 fp32 = 16 KB) into LDS, coalesced.
  __shared__ __align__(16) float4 xs[64 * 16];
  const long rbase = (long)blockIdx.x * 64;
  const float4* xg = (const float4*)(x + rbase * RNN_I);
#pragma unroll
  for (int jj = 0; jj < 4; ++jj) xs[tid + 256 * jj] = xg[tid + 256 * jj];
  __syncthreads();

  for (int r = 0; r < 64; ++r) {
    const float4* xr = xs + r * 16 + q * 4;
    float4 a0 = {0, 0, 0, 0}, a1 = {0, 0, 0, 0};
#pragma unroll
    for (int m = 0; m < 4; ++m) {
      const float4 xv = xr[m];
      fma4(a0, w[0][m], xv);
      fma4(a1, w[1][m], xv);
    }
    float s0 = hsum(a0), s1 = hsum(a1);
    s0 = dpp_add<0xB1>(s0); s0 = dpp_add<0x4E>(s0);
    s1 = dpp_add<0xB1>(s1); s1 = dpp_add<0x4E>(s1);
    const float own = (q & 1) ? s1 : s0;
    if (q < 2)
      xw[(rbase + r) * RNN_H + row_own] = own + bias;
  }
}

// ---------------------------------------------------------------------------
// Kernel 2: sequential scan. 1 block/batch, 512 threads (8 waves, 2/SIMD).
// thread -> (g=tid>>3: rows 2g,2g+1; j=tid&7: k-slice [16j,16j+16)):
// 8 float4 of U in regs (proven-resident size). 32 KB/step/CU h-broadcast.
// 3-stage DPP butterfly -> all 8 lanes hold both row sums; j<2 writes
// next-h (skewed), j==4,5 writes obuf. No global ops inside steps.
// xw chunk prefetched into regs one chunk ahead; obuf flushed in Phase A.
// ---------------------------------------------------------------------------
__global__ __launch_bounds__(512, 2) void rnn_scan(
    const float* xw,            // aliases `out` — no __restrict__
    float* out, float* __restrict__ hlast,
    const float* __restrict__ h0, const float* __restrict__ U) {
  const int b     = blockIdx.x;
  const int tid   = threadIdx.x;  // 0..511
  const int g     = tid >> 3;     // 0..63 : rows 2g, 2g+1
  const int j     = tid & 7;      // k-slice [16j, 16j+16)
  const int r_own = 2 * g + (j & 1);

  __shared__ __align__(16) float hbuf0[8 * 20];     // skewed h state
  __shared__ __align__(16) float hbuf1[8 * 20];
  __shared__ __align__(16) float xbuf[CH * RNN_H];  // 16 KB
  __shared__ __align__(16) float obuf[CH * RNN_H];  // 16 KB

  // U tile: rows 2g,2g+1, cols [16j,16j+16) -> 8 float4 (32 VGPRs)
  float4 u[2][4];
#pragma unroll
  for (int r = 0; r < 2; ++r) {
    const float4* Ur = (const float4*)(U + (2 * g + r) * RNN_H + 16 * j);
#pragma unroll
    for (int m = 0; m < 4; ++m) { u[r][m] = Ur[m]; pin4(u[r][m]); }
  }

  if (tid < RNN_H)
    hbuf0[(tid >> 4) * 20 + (tid & 15)] = h0[b * RNN_H + tid];

  const int hoff = (r_own >> 4) * 20 + (r_own & 15);  // skewed write slot
  const long base   = (long)b * RNN_T * RNN_H;
  const float4* xw4 = (const float4*)(xw + base);
  float4* out4      = (float4*)(out + base);
  float4* xb4       = (float4*)xbuf;
  const float4* ob4 = (const float4*)obuf;

  // Prologue: prefetch chunk 0 into regs (2 float4/thread).
  float4 p0 = xw4[tid], p1 = xw4[tid + 512];

  auto step = [&](const float* src, float* dst, int tc) {
    const float xv = xbuf[tc * RNN_H + r_own];   // no h dependency: issues early
    const float4* hp = (const float4*)(src + 20 * j);
    float4 a0 = {0, 0, 0, 0}, a1 = {0, 0, 0, 0};
#pragma unroll
    for (int m = 0; m < 4; ++m) {
      const float4 hv = hp[m];
      fma4(a0, u[0][m], hv);
      fma4(a1, u[1][m], hv);
    }
    float s0 = hsum(a0), s1 = hsum(a1);
    s0 = dpp_add<0xB1>(s0); s0 = dpp_add<0x4E>(s0); s0 = dpp_add<0x141>(s0);
    s1 = dpp_add<0xB1>(s1); s1 = dpp_add<0x4E>(s1); s1 = dpp_add<0x141>(s1);
    const float own = (j & 1) ? s1 : s0;
    const float val = fast_tanh(own + xv);
    if (j < 2) {
      dst[hoff] = val;                      // ds_write: next h state
    } else if ((j & 6) == 4) {              // j == 4,5
      obuf[tc * RNN_H + r_own] = val;       // ds_write: staged output
    }
    __syncthreads();
  };

  for (int c = 0; c < NCH; ++c) {
    // Phase A: commit prefetched chunk c to LDS; issue prefetch of c+1
    // (overlaps with the obuf flush); flush out chunk c-1.
    xb4[tid] = p0; xb4[tid + 512] = p1;
    if (c + 1 < NCH) {
      const float4* nx = xw4 + (long)(c + 1) * 1024;
      p0 = nx[tid]; p1 = nx[tid + 512];
    }
    if (c > 0) {
      out4[(long)(c - 1) * 1024 + tid]       = ob4[tid];
      out4[(long)(c - 1) * 1024 + tid + 512] = ob4[tid + 512];
    }
    __syncthreads();

    // Phase B: 32 steps, LDS-only traffic, compile-time h ping-pong.
    for (int tc = 0; tc < CH; tc += 2) {
      step(hbuf0, hbuf1, tc);
      step(hbuf1, hbuf0, tc + 1);
    }
  }

  // Final chunk flush + h_last (last step's barrier makes data visible)
  out4[(long)(NCH - 1) * 1024 + tid]       = ob4[tid];
  out4[(long)(NCH - 1) * 1024 + tid + 512] = ob4[tid + 512];
  if (tid < RNN_H)
    hlast[b * RNN_H + tid] = hbuf0[(tid >> 4) * 20 + (tid & 15)];
}

extern "C" void kernel_launch(void* const* d_in, const int* in_sizes, int n_in,
                              void* d_out, int out_size, void* d_ws, size_t ws_size,
                              hipStream_t stream) {
  const float* x    = (const float*)d_in[0];
  const float* h0   = (const float*)d_in[1];
  const float* W    = (const float*)d_in[2];
  const float* U    = (const float*)d_in[3];
  const float* b_ih = (const float*)d_in[4];
  const float* b_hh = (const float*)d_in[5];

  float* out   = (float*)d_out;                           // [B,T,H]
  float* hlast = out + (long)RNN_B * RNN_T * RNN_H;       // [B,H]

  // Stage 1: xw into the output region (read-before-write in scan, per chunk)
  rnn_xw_gemm<<<(RNN_B * RNN_T) / 64, 256, 0, stream>>>(x, W, b_ih, b_hh, out);
  // Stage 2: sequential recurrence, one block per batch element
  rnn_scan<<<RNN_B, 512, 0, stream>>>(out, out, hlast, h0, U);
}

// Round 10
// 752.213 us; speedup vs baseline: 1.1692x; 1.0647x over previous
//
#include <hip/hip_runtime.h>

// Vanilla tanh RNN. B=64, T=2048, I=64, H=128, fp32.
//   xw[b,t,h] = sum_i x[b,t,i]*W[h,i] + b_ih[h] + b_hh[h]
//   h_t = tanh(xw_t + h_{t-1} @ U^T);  outputs: ys [B,T,H], h_last [B,H]
//
// R12. Post-mortem R10 (691us scan, VGPR=36):
//  (1) pin4 is HARMFUL: R5 (no pin, 32-float tile) VGPR=52 resident;
//      R10 (pin, same tile) VGPR=36 evicted. The asm "+v" reference pins
//      homed u in memory. REMOVED everywhere.
//  (2) Scan time is invariant (650-762us) across 16/32/64KB-per-step LDS
//      volume and 32/64-float tiles -> neither lever is binding. The
//      shared skeleton (barrier + ds write/read latency + tanh chain)
//      must be the cost. Every observed VGPR<=64: allocator caps at the
//      8-wave budget, so all designs must fit <=64 VGPR.
// This round:
//  - scan: EXACTLY R10's mapping minus pin4 (isolates pin4's effect; u is
//    the proven-resident 32-float size; total regs ~60 <= 64 cap).
//    Plus xv software pipeline: next step's xbuf value is read BEFORE the
//    barrier and carried in a register -> one fewer post-barrier LDS read
//    on the serial chain.
//  - gemm: R10 minus pin4.
//  - rnn_skel DIAGNOSTIC (writes d_ws only, 512 steps): the scan's
//    barrier/ds/tanh skeleton with no FMA/reduce. Its per-step cycles
//    measure this family's floor: ~160cyc -> headroom via VALU/ds work;
//    ~600cyc -> the skeleton IS the 780cyc and the family needs
//    restructuring. Read from dispatch table or total-dur residual.
// (R15 = R12 resubmitted verbatim: R12/R13 hit GPUAcquisitionTimeout,
//  R14 hit "MI355X container failed twice" — no measurement yet. If
//  container failures persist ONLY on this revision, suspect rnn_skel
//  and drop it next round.)

#define RNN_B 64
#define RNN_T 2048
#define RNN_I 64
#define RNN_H 128
#define CH    32            // timesteps per staged chunk
#define NCH   (RNN_T / CH)  // 64 chunks

__device__ __forceinline__ float fast_tanh(float x) {
  // tanh(x) = 1 - 2/(e^{2x}+1);  e^{2x} = exp2(x * 2*log2(e))
  float e = __builtin_amdgcn_exp2f(x * 2.885390081777927f);
  return 1.0f - 2.0f * __builtin_amdgcn_rcpf(e + 1.0f);
}

template <int CTRL>
__device__ __forceinline__ float dpp_add(float s) {
  int o = __builtin_amdgcn_mov_dpp(__float_as_int(s), CTRL, 0xF, 0xF, true);
  return s + __int_as_float(o);
}

__device__ __forceinline__ void fma4(float4& a, const float4 u, const float4 h) {
  a.x = fmaf(u.x, h.x, a.x);
  a.y = fmaf(u.y, h.y, a.y);
  a.z = fmaf(u.z, h.z, a.z);
  a.w = fmaf(u.w, h.w, a.w);
}

__device__ __forceinline__ float hsum(const float4 a) {
  return (a.x + a.y) + (a.z + a.w);
}

// ---------------------------------------------------------------------------
// Kernel 1: xw = x @ W^T + (b_ih + b_hh).  M=B*T=131072, N=128, K=64.
// 2048 blocks x 256 threads, 64 x-rows/block, 2 blocks/CU.
// thread -> (g=tid>>2: rows 2g,2g+1; q=tid&3: cols [16q,16q+16)):
// 8 float4 of W in regs (32 VGPR — proven-resident size, no pins).
// Quad butterfly (xor1+xor2) -> all 4 lanes hold both row sums; lanes
// q<2 store row 2g+q -> 32 contiguous dwords/wave.
// ---------------------------------------------------------------------------
__global__ __launch_bounds__(256, 2) void rnn_xw_gemm(
    const float* __restrict__ x, const float* __restrict__ W,
    const float* __restrict__ b_ih, const float* __restrict__ b_hh,
    float* __restrict__ xw) {
  const int tid = threadIdx.x;
  const int g   = tid >> 2;   // 0..63 : rows 2g, 2g+1
  const int q   = tid & 3;    // col slice [16q, 16q+16)

  // W tile: rows 2g,2g+1, cols [16q,16q+16) -> 8 float4 (32 VGPRs)
  float4 w[2][4];
#pragma unroll
  for (int r = 0; r < 2; ++r) {
    const float4* Wr = (const float4*)(W + (2 * g + r) * RNN_I + 16 * q);
#pragma unroll
    for (int m = 0; m < 4; ++m) w[r][m] = Wr[m];
  }
  const int row_own = 2 * g + (q & 1);
  const float bias  = b_ih[row_own] + b_hh[row_own];

  // Stage 64 rows of x (64x64 fp32 = 16 KB) into LDS, coalesced.
  __shared__ __align__(16) float4 xs[64 * 16];
  const long rbase = (long)blockIdx.x * 64;
  const float4* xg = (const float4*)(x + rbase * RNN_I);
#pragma unroll
  for (int jj = 0; jj < 4; ++jj) xs[tid + 256 * jj] = xg[tid + 256 * jj];
  __syncthreads();

  for (int r = 0; r < 64; ++r) {
    const float4* xr = xs + r * 16 + q * 4;
    float4 a0 = {0, 0, 0, 0}, a1 = {0, 0, 0, 0};
#pragma unroll
    for (int m = 0; m < 4; ++m) {
      const float4 xv = xr[m];
      fma4(a0, w[0][m], xv);
      fma4(a1, w[1][m], xv);
    }
    float s0 = hsum(a0), s1 = hsum(a1);
    s0 = dpp_add<0xB1>(s0); s0 = dpp_add<0x4E>(s0);
    s1 = dpp_add<0xB1>(s1); s1 = dpp_add<0x4E>(s1);
    const float own = (q & 1) ? s1 : s0;
    if (q < 2)
      xw[(rbase + r) * RNN_H + row_own] = own + bias;
  }
}

// ---------------------------------------------------------------------------
// Kernel 2: sequential scan. 1 block/batch, 512 threads (8 waves, 2/SIMD).
// thread -> (g=tid>>3: rows 2g,2g+1; j=tid&7: k-slice [16j,16j+16)):
// 8 float4 of U in regs (32 VGPR, no pins). 32 KB/step/CU h-broadcast.
// 3-stage DPP butterfly (xor1 0xB1, xor2 0x4E, mirror 0x141) -> all 8
// lanes hold both row sums; j<2 writes next-h (skewed), j==4,5 writes
// obuf. xv for step t+1 is read pre-barrier during step t (register
// carry) so the post-barrier chain starts at the h ds_read.
// h skew: h[k] at float off (k>>4)*20+(k&15); slice bases 20j mod 32
// all distinct -> conflict-free broadcast.
// ---------------------------------------------------------------------------
__global__ __launch_bounds__(512, 2) void rnn_scan(
    const float* xw,            // aliases `out` — no __restrict__
    float* out, float* __restrict__ hlast,
    const float* __restrict__ h0, const float* __restrict__ U) {
  const int b     = blockIdx.x;
  const int tid   = threadIdx.x;  // 0..511
  const int g     = tid >> 3;     // 0..63 : rows 2g, 2g+1
  const int j     = tid & 7;      // k-slice [16j, 16j+16)
  const int r_own = 2 * g + (j & 1);

  __shared__ __align__(16) float hbuf0[8 * 20];     // skewed h state
  __shared__ __align__(16) float hbuf1[8 * 20];
  __shared__ __align__(16) float xbuf[CH * RNN_H];  // 16 KB
  __shared__ __align__(16) float obuf[CH * RNN_H];  // 16 KB

  // U tile: rows 2g,2g+1, cols [16j,16j+16) -> 8 float4 (32 VGPRs)
  float4 u[2][4];
#pragma unroll
  for (int r = 0; r < 2; ++r) {
    const float4* Ur = (const float4*)(U + (2 * g + r) * RNN_H + 16 * j);
#pragma unroll
    for (int m = 0; m < 4; ++m) u[r][m] = Ur[m];
  }

  if (tid < RNN_H)
    hbuf0[(tid >> 4) * 20 + (tid & 15)] = h0[b * RNN_H + tid];

  const int hoff = (r_own >> 4) * 20 + (r_own & 15);  // skewed write slot
  const long base   = (long)b * RNN_T * RNN_H;
  const float4* xw4 = (const float4*)(xw + base);
  float4* out4      = (float4*)(out + base);
  float4* xb4       = (float4*)xbuf;
  const float4* ob4 = (const float4*)obuf;

  // Prologue: prefetch chunk 0 into regs (2 float4/thread).
  float4 p0 = xw4[tid], p1 = xw4[tid + 512];

  float xv_cur;  // xw value for the CURRENT step, read one step ahead

  auto step = [&](const float* src, float* dst, int tc) {
    const float4* hp = (const float4*)(src + 20 * j);
    float4 a0 = {0, 0, 0, 0}, a1 = {0, 0, 0, 0};
#pragma unroll
    for (int m = 0; m < 4; ++m) {
      const float4 hv = hp[m];
      fma4(a0, u[0][m], hv);
      fma4(a1, u[1][m], hv);
    }
    // Pre-barrier read of NEXT step's xv (xbuf stable within the chunk;
    // wraps at the last step — overwritten after the next chunk stages).
    const float xv_next = xbuf[((tc + 1) & (CH - 1)) * RNN_H + r_own];
    float s0 = hsum(a0), s1 = hsum(a1);
    s0 = dpp_add<0xB1>(s0); s0 = dpp_add<0x4E>(s0); s0 = dpp_add<0x141>(s0);
    s1 = dpp_add<0xB1>(s1); s1 = dpp_add<0x4E>(s1); s1 = dpp_add<0x141>(s1);
    const float own = (j & 1) ? s1 : s0;
    const float val = fast_tanh(own + xv_cur);
    if (j < 2) {
      dst[hoff] = val;                      // ds_write: next h state
    } else if ((j & 6) == 4) {              // j == 4,5
      obuf[tc * RNN_H + r_own] = val;       // ds_write: staged output
    }
    __syncthreads();
    xv_cur = xv_next;
  };

  for (int c = 0; c < NCH; ++c) {
    // Phase A: commit prefetched chunk c to LDS; issue prefetch of c+1
    // (overlaps with the obuf flush); flush out chunk c-1.
    xb4[tid] = p0; xb4[tid + 512] = p1;
    if (c + 1 < NCH) {
      const float4* nx = xw4 + (long)(c + 1) * 1024;
      p0 = nx[tid]; p1 = nx[tid + 512];
    }
    if (c > 0) {
      out4[(long)(c - 1) * 1024 + tid]       = ob4[tid];
      out4[(long)(c - 1) * 1024 + tid + 512] = ob4[tid + 512];
    }
    __syncthreads();

    // Phase B: 32 steps, LDS-only traffic, compile-time h ping-pong.
    xv_cur = xbuf[r_own];  // tc = 0 of this chunk
    for (int tc = 0; tc < CH; tc += 2) {
      step(hbuf0, hbuf1, tc);
      step(hbuf1, hbuf0, tc + 1);
    }
  }

  // Final chunk flush + h_last (last step's barrier makes data visible)
  out4[(long)(NCH - 1) * 1024 + tid]       = ob4[tid];
  out4[(long)(NCH - 1) * 1024 + tid + 512] = ob4[tid + 512];
  if (tid < RNN_H)
    hlast[b * RNN_H + tid] = hbuf0[(tid >> 4) * 20 + (tid & 15)];
}

// ---------------------------------------------------------------------------
// DIAGNOSTIC: the scan's sync skeleton — barrier + 4x ds_read_b128 +
// tanh + ds_write per step, NO FMA/reduce. 512 steps (1/4 of T).
// Writes only d_ws. Per-step cycles = dur * 2400 / 512 measures the
// family's floor. All values flow into the final ws write (no DCE).
// ---------------------------------------------------------------------------
__global__ __launch_bounds__(512, 2) void rnn_skel(float* __restrict__ ws) {
  const int tid   = threadIdx.x;
  const int g     = tid >> 3;
  const int j     = tid & 7;
  const int r_own = 2 * g + (j & 1);
  const int hoff  = (r_own >> 4) * 20 + (r_own & 15);

  __shared__ __align__(16) float hbuf0[8 * 20];
  __shared__ __align__(16) float hbuf1[8 * 20];
  __shared__ __align__(16) float obuf[RNN_H];

  if (tid < 160) { hbuf0[tid] = (float)tid * 0.001f; hbuf1[tid] = 0.0f; }
  if (tid < RNN_H) obuf[tid] = 0.0f;
  __syncthreads();

  auto sk = [&](const float* src, float* dst) {
    const float4* hp = (const float4*)(src + 20 * j);
    const float4 h0 = hp[0], h1 = hp[1], h2 = hp[2], h3 = hp[3];
    const float val = fast_tanh((h0.x + h1.y) + (h2.z + h3.w));
    if (j < 2) dst[hoff] = val;
    else if ((j & 6) == 4) obuf[r_own] = val;
    __syncthreads();
  };

  for (int t = 0; t < 512; t += 2) { sk(hbuf0, hbuf1); sk(hbuf1, hbuf0); }

  if (tid < RNN_H)
    ws[blockIdx.x * RNN_H + tid] =
        hbuf0[(tid >> 4) * 20 + (tid & 15)] + obuf[tid];
}

extern "C" void kernel_launch(void* const* d_in, const int* in_sizes, int n_in,
                              void* d_out, int out_size, void* d_ws, size_t ws_size,
                              hipStream_t stream) {
  const float* x    = (const float*)d_in[0];
  const float* h0   = (const float*)d_in[1];
  const float* W    = (const float*)d_in[2];
  const float* U    = (const float*)d_in[3];
  const float* b_ih = (const float*)d_in[4];
  const float* b_hh = (const float*)d_in[5];

  float* out   = (float*)d_out;                           // [B,T,H]
  float* hlast = out + (long)RNN_B * RNN_T * RNN_H;       // [B,H]

  // Stage 1: xw into the output region (read-before-write in scan, per chunk)
  rnn_xw_gemm<<<(RNN_B * RNN_T) / 64, 256, 0, stream>>>(x, W, b_ih, b_hh, out);
  // Stage 2: sequential recurrence, one block per batch element
  rnn_scan<<<RNN_B, 512, 0, stream>>>(out, out, hlast, h0, U);
  // Diagnostic skeleton (timing probe only; writes scratch workspace)
  if (ws_size >= (size_t)RNN_B * RNN_H * sizeof(float))
    rnn_skel<<<RNN_B, 512, 0, stream>>>((float*)d_ws);
}

// Round 11
// 746.181 us; speedup vs baseline: 1.1787x; 1.0081x over previous
//
#include <hip/hip_runtime.h>

// Vanilla tanh RNN. B=64, T=2048, I=64, H=128, fp32.
//   xw[b,t,h] = sum_i x[b,t,i]*W[h,i] + b_ih[h] + b_hh[h]
//   h_t = tanh(xw_t + h_{t-1} @ U^T);  outputs: ys [B,T,H], h_last [B,H]
//
// R16. Post-mortem R12 (scan 568us=666cyc/step, VGPR=40, skel probe 74us):
//  - pin4 removal CONFIRMED (-83us): u resident at VGPR=40.
//  - SKELETON PROBE: 74us/512 steps = 347 cyc/step with NO fma/reduce ->
//    matches 32 ds_read_b128 instrs x ~12cyc (m134). The scan is LDS-
//    INSTRUCTION-ISSUE bound: DS pipe runs per-wave instrs serially;
//    broadcast/data volume irrelevant. Full scan DS budget: 32x12(reads)
//    + 24x6(xv+hwrite+obuf) = 528 of the 666 cyc. Explains R5-R12
//    invariance (all had ~same DS instr counts).
// Fix: halve read instrs. Thread tile (R=2 x C=16) -> (R=4 rows x C=8
// cols): same 32-float proven-resident U tile, h-slice = 8 floats ->
// 2 ds_read_b128 (was 4): 32->16 read instrs/step/CU. Reduce widens to
// 16 lanes: 4-stage all-DPP rotate (row_ror:1,2,4,8 = 0x121/2/4/8).
// New h skew k+4*(k>>5): slice bases pair 2-way max in banks (free,
// m136); offsets all %4==0 floats -> b128-aligned. Writers: c<4 -> h',
// c in 4..7 -> obuf. Same change in gemm (8-lane reduce keeps proven
// {0xB1,0x4E,0x141}). Phase A prefetch + xv pipeline + barriers
// unchanged from R12 (single-variable experiment). Skel probe removed.

#define RNN_B 64
#define RNN_T 2048
#define RNN_I 64
#define RNN_H 128
#define CH    32            // timesteps per staged chunk
#define NCH   (RNN_T / CH)  // 64 chunks

__device__ __forceinline__ float fast_tanh(float x) {
  // tanh(x) = 1 - 2/(e^{2x}+1);  e^{2x} = exp2(x * 2*log2(e))
  float e = __builtin_amdgcn_exp2f(x * 2.885390081777927f);
  return 1.0f - 2.0f * __builtin_amdgcn_rcpf(e + 1.0f);
}

template <int CTRL>
__device__ __forceinline__ float dpp_add(float s) {
  int o = __builtin_amdgcn_mov_dpp(__float_as_int(s), CTRL, 0xF, 0xF, true);
  return s + __int_as_float(o);
}

// 8-term dot: (u0,u1) . (h0,h1), scalar fma chain (4 regs of accum saved
// vs float4 accums -> keeps u resident under the ~64-VGPR allocator cap).
__device__ __forceinline__ float dot8(const float4 u0, const float4 u1,
                                      const float4 h0, const float4 h1) {
  float s = u0.x * h0.x;
  s = fmaf(u0.y, h0.y, s);
  s = fmaf(u0.z, h0.z, s);
  s = fmaf(u0.w, h0.w, s);
  s = fmaf(u1.x, h1.x, s);
  s = fmaf(u1.y, h1.y, s);
  s = fmaf(u1.z, h1.z, s);
  s = fmaf(u1.w, h1.w, s);
  return s;
}

// ---------------------------------------------------------------------------
// Kernel 1: xw = x @ W^T + (b_ih + b_hh).  M=B*T=131072, N=128, K=64.
// 2048 blocks x 256 threads, 64 x-rows/block.
// thread -> (g=tid>>3: rows 4g..4g+3; c=tid&7: cols [8c,8c+8) of K=64):
// w[4][2] float4 (32 VGPR). Per x-row: 2 ds_read_b128 (8 instr/CU-iter,
// was 16), 32 fma, 3-stage 8-lane butterfly {xor1,xor2,xor7}; lanes c<4
// store row 4g+c -> 32 contiguous dwords per half-wave.
// ---------------------------------------------------------------------------
__global__ __launch_bounds__(256, 2) void rnn_xw_gemm(
    const float* __restrict__ x, const float* __restrict__ W,
    const float* __restrict__ b_ih, const float* __restrict__ b_hh,
    float* __restrict__ xw) {
  const int tid = threadIdx.x;
  const int g   = tid >> 3;   // 0..31 : rows 4g..4g+3
  const int c   = tid & 7;    // col slice [8c, 8c+8)
  const int r_own = 4 * g + (c & 3);

  // W tile: rows 4g..4g+3, cols [8c,8c+8) -> 8 float4 (32 VGPRs)
  float4 w[4][2];
#pragma unroll
  for (int r = 0; r < 4; ++r) {
    const float4* Wr = (const float4*)(W + (4 * g + r) * RNN_I + 8 * c);
    w[r][0] = Wr[0];
    w[r][1] = Wr[1];
  }
  const float bias = b_ih[r_own] + b_hh[r_own];

  // Stage 64 rows of x (64x64 fp32 = 16 KB) into LDS, coalesced.
  __shared__ __align__(16) float4 xs[64 * 16];
  const long rbase = (long)blockIdx.x * 64;
  const float4* xg = (const float4*)(x + rbase * RNN_I);
#pragma unroll
  for (int jj = 0; jj < 4; ++jj) xs[tid + 256 * jj] = xg[tid + 256 * jj];
  __syncthreads();

  for (int r = 0; r < 64; ++r) {
    const float4* xr = xs + r * 16 + 2 * c;
    const float4 hv0 = xr[0], hv1 = xr[1];
    float s0 = dot8(w[0][0], w[0][1], hv0, hv1);
    float s1 = dot8(w[1][0], w[1][1], hv0, hv1);
    float s2 = dot8(w[2][0], w[2][1], hv0, hv1);
    float s3 = dot8(w[3][0], w[3][1], hv0, hv1);
    // 8-lane butterfly: xor1, xor2, xor7-within-8 (proven masks)
    s0 = dpp_add<0xB1>(s0); s0 = dpp_add<0x4E>(s0); s0 = dpp_add<0x141>(s0);
    s1 = dpp_add<0xB1>(s1); s1 = dpp_add<0x4E>(s1); s1 = dpp_add<0x141>(s1);
    s2 = dpp_add<0xB1>(s2); s2 = dpp_add<0x4E>(s2); s2 = dpp_add<0x141>(s2);
    s3 = dpp_add<0xB1>(s3); s3 = dpp_add<0x4E>(s3); s3 = dpp_add<0x141>(s3);
    const float own = (c & 2) ? ((c & 1) ? s3 : s2)
                              : ((c & 1) ? s1 : s0);
    if (c < 4)
      xw[(rbase + r) * RNN_H + r_own] = own + bias;
  }
}

// ---------------------------------------------------------------------------
// Kernel 2: sequential scan. 1 block/batch, 512 threads (8 waves, 2/SIMD).
// thread -> (g=tid>>4: rows 4g..4g+3; c=tid&15: cols [8c,8c+8)):
// u[4][2] float4 (32 VGPR, proven-resident). Per step: 2 ds_read_b128
// (16 read instrs/step/CU, was 32 = the R12 bottleneck), 32 fma,
// 4-stage 16-lane DPP rotate-reduce (row_ror:1,2,4,8) -> all 16 lanes
// hold all 4 row sums; c<4 writes next-h (skewed), c in 4..7 writes
// obuf. h skew: h[k] at k+4*(k>>5) (140 floats): slice bases 2-way max
// per bank-quad (free), all float4-aligned. xv pipelined pre-barrier.
// ---------------------------------------------------------------------------
__global__ __launch_bounds__(512, 2) void rnn_scan(
    const float* xw,            // aliases `out` — no __restrict__
    float* out, float* __restrict__ hlast,
    const float* __restrict__ h0, const float* __restrict__ U) {
  const int b     = blockIdx.x;
  const int tid   = threadIdx.x;  // 0..511
  const int g     = tid >> 4;     // 0..31 : rows 4g..4g+3
  const int c     = tid & 15;     // col slice [8c, 8c+8)
  const int r_own = 4 * g + (c & 3);

  __shared__ __align__(16) float hbuf0[140];        // skewed h state
  __shared__ __align__(16) float hbuf1[140];
  __shared__ __align__(16) float xbuf[CH * RNN_H];  // 16 KB
  __shared__ __align__(16) float obuf[CH * RNN_H];  // 16 KB

  // U tile: rows 4g..4g+3, cols [8c,8c+8) -> 8 float4 (32 VGPRs)
  float4 u[4][2];
#pragma unroll
  for (int r = 0; r < 4; ++r) {
    const float4* Ur = (const float4*)(U + (4 * g + r) * RNN_H + 8 * c);
    u[r][0] = Ur[0];
    u[r][1] = Ur[1];
  }

  if (tid < RNN_H)
    hbuf0[tid + 4 * (tid >> 5)] = h0[b * RNN_H + tid];

  const int hrd = 8 * c + 4 * (c >> 2);          // skewed read base (floats)
  const int hwr = r_own + 4 * (r_own >> 5);      // skewed write slot
  const long base   = (long)b * RNN_T * RNN_H;
  const float4* xw4 = (const float4*)(xw + base);
  float4* out4      = (float4*)(out + base);
  float4* xb4       = (float4*)xbuf;
  const float4* ob4 = (const float4*)obuf;

  // Prologue: prefetch chunk 0 into regs (2 float4/thread).
  float4 p0 = xw4[tid], p1 = xw4[tid + 512];

  float xv_cur;  // xw value for the CURRENT step, read one step ahead

  auto step = [&](const float* src, float* dst, int tc) {
    const float4* hp = (const float4*)(src + hrd);
    const float4 hv0 = hp[0], hv1 = hp[1];
    float s0 = dot8(u[0][0], u[0][1], hv0, hv1);
    float s1 = dot8(u[1][0], u[1][1], hv0, hv1);
    float s2 = dot8(u[2][0], u[2][1], hv0, hv1);
    float s3 = dot8(u[3][0], u[3][1], hv0, hv1);
    // Pre-barrier read of NEXT step's xv (xbuf stable within the chunk).
    const float xv_next = xbuf[((tc + 1) & (CH - 1)) * RNN_H + r_own];
    // 16-lane rotate-reduce: ror 1,2,4,8 within the DPP row -> full sums
    s0 = dpp_add<0x121>(s0); s0 = dpp_add<0x122>(s0);
    s0 = dpp_add<0x124>(s0); s0 = dpp_add<0x128>(s0);
    s1 = dpp_add<0x121>(s1); s1 = dpp_add<0x122>(s1);
    s1 = dpp_add<0x124>(s1); s1 = dpp_add<0x128>(s1);
    s2 = dpp_add<0x121>(s2); s2 = dpp_add<0x122>(s2);
    s2 = dpp_add<0x124>(s2); s2 = dpp_add<0x128>(s2);
    s3 = dpp_add<0x121>(s3); s3 = dpp_add<0x122>(s3);
    s3 = dpp_add<0x124>(s3); s3 = dpp_add<0x128>(s3);
    const float own = (c & 2) ? ((c & 1) ? s3 : s2)
                              : ((c & 1) ? s1 : s0);
    const float val = fast_tanh(own + xv_cur);
    if (c < 4) {
      dst[hwr] = val;                       // ds_write: next h state
    } else if (c < 8) {                     // c == 4..7
      obuf[tc * RNN_H + r_own] = val;       // ds_write: staged output
    }
    __syncthreads();
    xv_cur = xv_next;
  };

  for (int ch = 0; ch < NCH; ++ch) {
    // Phase A: commit prefetched chunk to LDS; issue prefetch of next
    // (overlaps with the obuf flush); flush out chunk ch-1.
    xb4[tid] = p0; xb4[tid + 512] = p1;
    if (ch + 1 < NCH) {
      const float4* nx = xw4 + (long)(ch + 1) * 1024;
      p0 = nx[tid]; p1 = nx[tid + 512];
    }
    if (ch > 0) {
      out4[(long)(ch - 1) * 1024 + tid]       = ob4[tid];
      out4[(long)(ch - 1) * 1024 + tid + 512] = ob4[tid + 512];
    }
    __syncthreads();

    // Phase B: 32 steps, LDS-only traffic, compile-time h ping-pong.
    xv_cur = xbuf[r_own];  // tc = 0 of this chunk
    for (int tc = 0; tc < CH; tc += 2) {
      step(hbuf0, hbuf1, tc);
      step(hbuf1, hbuf0, tc + 1);
    }
  }

  // Final chunk flush + h_last (last step's barrier makes data visible)
  out4[(long)(NCH - 1) * 1024 + tid]       = ob4[tid];
  out4[(long)(NCH - 1) * 1024 + tid + 512] = ob4[tid + 512];
  if (tid < RNN_H)
    hlast[b * RNN_H + tid] = hbuf0[tid + 4 * (tid >> 5)];
}

extern "C" void kernel_launch(void* const* d_in, const int* in_sizes, int n_in,
                              void* d_out, int out_size, void* d_ws, size_t ws_size,
                              hipStream_t stream) {
  const float* x    = (const float*)d_in[0];
  const float* h0   = (const float*)d_in[1];
  const float* W    = (const float*)d_in[2];
  const float* U    = (const float*)d_in[3];
  const float* b_ih = (const float*)d_in[4];
  const float* b_hh = (const float*)d_in[5];

  float* out   = (float*)d_out;                           // [B,T,H]
  float* hlast = out + (long)RNN_B * RNN_T * RNN_H;       // [B,H]

  // Stage 1: xw into the output region (read-before-write in scan, per chunk)
  rnn_xw_gemm<<<(RNN_B * RNN_T) / 64, 256, 0, stream>>>(x, W, b_ih, b_hh, out);
  // Stage 2: sequential recurrence, one block per batch element
  rnn_scan<<<RNN_B, 512, 0, stream>>>(out, out, hlast, h0, U);
}

// Round 13
// 661.475 us; speedup vs baseline: 1.3296x; 1.1281x over previous
//
#include <hip/hip_runtime.h>

// Vanilla tanh RNN. B=64, T=2048, I=64, H=128, fp32.
//   xw[b,t,h] = sum_i x[b,t,i]*W[h,i] + b_ih[h] + b_hh[h]
//   h_t = tanh(xw_t + h_{t-1} @ U^T);  outputs: ys [B,T,H], h_last [B,H]
//
// R17. Post-mortem R16 (scan 629us, VGPR=36, BANK_CONFLICT 512->8.4M):
//  - C=8 slices are STRUCTURALLY >=2-way conflicted for b128 (16 lanes x
//    4 banks = 64 slots > 32 banks). The +61us == the 64 conflict-cyc/step.
//  - Read-instr halving bought ~0: broadcast b128 with 8 distinct addrs
//    is ~cheap (128B/instr), not m134's 12cyc (that was 64 distinct).
//    R12's 666 = DS ~150 + VALU-issue ~200 (256 fma-instr/CU = minimum)
//    + latency/barrier skeleton ~300 (lockstep waves share all stalls).
// Fix this round (core scan = R12 EXACTLY, proven 568us/VGPR=40):
//  (a) all scan barriers -> raw "s_waitcnt lgkmcnt(0); s_barrier".
//      __syncthreads drains vmcnt(0) too, so each chunk's prefetch
//      (2 HBM loads issued in Phase A) stalled its own barrier ~700cyc.
//      Phase-B steps have NO global ops -> lgkm-only is sufficient;
//      prefetch/flush latency now hides under the 32 steps. Compiler
//      still auto-inserts vmcnt waits before p0/p1 are consumed.
//  (b) gemm: #pragma unroll 4 on the row loop (4 iters' ds_reads issue
//      together -> latency amortized). Separate dispatch = attribution.
// (R18 = R17 resubmitted verbatim: R17 bench hit GPUAcquisitionTimeout,
//  no measurement was taken.)

#define RNN_B 64
#define RNN_T 2048
#define RNN_I 64
#define RNN_H 128
#define CH    32            // timesteps per staged chunk
#define NCH   (RNN_T / CH)  // 64 chunks

__device__ __forceinline__ float fast_tanh(float x) {
  // tanh(x) = 1 - 2/(e^{2x}+1);  e^{2x} = exp2(x * 2*log2(e))
  float e = __builtin_amdgcn_exp2f(x * 2.885390081777927f);
  return 1.0f - 2.0f * __builtin_amdgcn_rcpf(e + 1.0f);
}

template <int CTRL>
__device__ __forceinline__ float dpp_add(float s) {
  int o = __builtin_amdgcn_mov_dpp(__float_as_int(s), CTRL, 0xF, 0xF, true);
  return s + __int_as_float(o);
}

__device__ __forceinline__ void fma4(float4& a, const float4 u, const float4 h) {
  a.x = fmaf(u.x, h.x, a.x);
  a.y = fmaf(u.y, h.y, a.y);
  a.z = fmaf(u.z, h.z, a.z);
  a.w = fmaf(u.w, h.w, a.w);
}

__device__ __forceinline__ float hsum(const float4 a) {
  return (a.x + a.y) + (a.z + a.w);
}

// Workgroup barrier WITHOUT the vmcnt(0) drain __syncthreads implies.
// Phase-B steps touch only LDS; outstanding global prefetch/flush ops may
// legally float across. "memory" clobber stops compiler reordering of
// memory ops across the barrier; compiler auto-waits vmcnt before any
// USE of an outstanding load's result.
__device__ __forceinline__ void barrier_lgkm() {
  asm volatile("s_waitcnt lgkmcnt(0)\n\ts_barrier" ::: "memory");
}

// ---------------------------------------------------------------------------
// Kernel 1: xw = x @ W^T + (b_ih + b_hh).  M=B*T=131072, N=128, K=64.
// 2048 blocks x 256 threads, 64 x-rows/block, 2 blocks/CU.
// thread -> (g=tid>>2: rows 2g,2g+1; q=tid&3: cols [16q,16q+16)):
// 8 float4 of W in regs (32 VGPR, proven-resident). Quad butterfly
// (xor1+xor2) -> all 4 lanes hold both row sums; lanes q<2 store row
// 2g+q -> 32 contiguous dwords/wave. r-loop unrolled x4 so 4 iters'
// ds_reads issue back-to-back (read latency amortized).
// ---------------------------------------------------------------------------
__global__ __launch_bounds__(256, 2) void rnn_xw_gemm(
    const float* __restrict__ x, const float* __restrict__ W,
    const float* __restrict__ b_ih, const float* __restrict__ b_hh,
    float* __restrict__ xw) {
  const int tid = threadIdx.x;
  const int g   = tid >> 2;   // 0..63 : rows 2g, 2g+1
  const int q   = tid & 3;    // col slice [16q, 16q+16)

  // W tile: rows 2g,2g+1, cols [16q,16q+16) -> 8 float4 (32 VGPRs)
  float4 w[2][4];
#pragma unroll
  for (int r = 0; r < 2; ++r) {
    const float4* Wr = (const float4*)(W + (2 * g + r) * RNN_I + 16 * q);
#pragma unroll
    for (int m = 0; m < 4; ++m) w[r][m] = Wr[m];
  }
  const int row_own = 2 * g + (q & 1);
  const float bias  = b_ih[row_own] + b_hh[row_own];

  // Stage 64 rows of x (64x64 fp32 = 16 KB) into LDS, coalesced.
  __shared__ __align__(16) float4 xs[64 * 16];
  const long rbase = (long)blockIdx.x * 64;
  const float4* xg = (const float4*)(x + rbase * RNN_I);
#pragma unroll
  for (int jj = 0; jj < 4; ++jj) xs[tid + 256 * jj] = xg[tid + 256 * jj];
  __syncthreads();

#pragma unroll 4
  for (int r = 0; r < 64; ++r) {
    const float4* xr = xs + r * 16 + q * 4;
    float4 a0 = {0, 0, 0, 0}, a1 = {0, 0, 0, 0};
#pragma unroll
    for (int m = 0; m < 4; ++m) {
      const float4 xv = xr[m];
      fma4(a0, w[0][m], xv);
      fma4(a1, w[1][m], xv);
    }
    float s0 = hsum(a0), s1 = hsum(a1);
    s0 = dpp_add<0xB1>(s0); s0 = dpp_add<0x4E>(s0);
    s1 = dpp_add<0xB1>(s1); s1 = dpp_add<0x4E>(s1);
    const float own = (q & 1) ? s1 : s0;
    if (q < 2)
      xw[(rbase + r) * RNN_H + row_own] = own + bias;
  }
}

// ---------------------------------------------------------------------------
// Kernel 2: sequential scan. 1 block/batch, 512 threads (8 waves, 2/SIMD).
// == R12's proven core (568us, VGPR=40, conflicts ~0) with lgkm-only
// barriers. thread -> (g=tid>>3: rows 2g,2g+1; j=tid&7: cols [16j,16j+16)):
// 8 float4 of U in regs. 4x ds_read_b128/step (20j skew: 8 distinct
// bank-quads, conflict-free). 3-stage DPP butterfly {0xB1,0x4E,0x141};
// j<2 writes next-h, j==4,5 writes obuf. xv pipelined pre-barrier.
// ---------------------------------------------------------------------------
__global__ __launch_bounds__(512, 2) void rnn_scan(
    const float* xw,            // aliases `out` — no __restrict__
    float* out, float* __restrict__ hlast,
    const float* __restrict__ h0, const float* __restrict__ U) {
  const int b     = blockIdx.x;
  const int tid   = threadIdx.x;  // 0..511
  const int g     = tid >> 3;     // 0..63 : rows 2g, 2g+1
  const int j     = tid & 7;      // k-slice [16j, 16j+16)
  const int r_own = 2 * g + (j & 1);

  __shared__ __align__(16) float hbuf0[8 * 20];     // skewed h state
  __shared__ __align__(16) float hbuf1[8 * 20];
  __shared__ __align__(16) float xbuf[CH * RNN_H];  // 16 KB
  __shared__ __align__(16) float obuf[CH * RNN_H];  // 16 KB

  // U tile: rows 2g,2g+1, cols [16j,16j+16) -> 8 float4 (32 VGPRs)
  float4 u[2][4];
#pragma unroll
  for (int r = 0; r < 2; ++r) {
    const float4* Ur = (const float4*)(U + (2 * g + r) * RNN_H + 16 * j);
#pragma unroll
    for (int m = 0; m < 4; ++m) u[r][m] = Ur[m];
  }

  if (tid < RNN_H)
    hbuf0[(tid >> 4) * 20 + (tid & 15)] = h0[b * RNN_H + tid];

  const int hoff = (r_own >> 4) * 20 + (r_own & 15);  // skewed write slot
  const long base   = (long)b * RNN_T * RNN_H;
  const float4* xw4 = (const float4*)(xw + base);
  float4* out4      = (float4*)(out + base);
  float4* xb4       = (float4*)xbuf;
  const float4* ob4 = (const float4*)obuf;

  // Prologue: prefetch chunk 0 into regs (2 float4/thread).
  float4 p0 = xw4[tid], p1 = xw4[tid + 512];

  float xv_cur;  // xw value for the CURRENT step, read one step ahead

  auto step = [&](const float* src, float* dst, int tc) {
    const float4* hp = (const float4*)(src + 20 * j);
    float4 a0 = {0, 0, 0, 0}, a1 = {0, 0, 0, 0};
#pragma unroll
    for (int m = 0; m < 4; ++m) {
      const float4 hv = hp[m];
      fma4(a0, u[0][m], hv);
      fma4(a1, u[1][m], hv);
    }
    // Pre-barrier read of NEXT step's xv (xbuf stable within the chunk;
    // wraps at the last step — overwritten after the next chunk stages).
    const float xv_next = xbuf[((tc + 1) & (CH - 1)) * RNN_H + r_own];
    float s0 = hsum(a0), s1 = hsum(a1);
    s0 = dpp_add<0xB1>(s0); s0 = dpp_add<0x4E>(s0); s0 = dpp_add<0x141>(s0);
    s1 = dpp_add<0xB1>(s1); s1 = dpp_add<0x4E>(s1); s1 = dpp_add<0x141>(s1);
    const float own = (j & 1) ? s1 : s0;
    const float val = fast_tanh(own + xv_cur);
    if (j < 2) {
      dst[hoff] = val;                      // ds_write: next h state
    } else if ((j & 6) == 4) {              // j == 4,5
      obuf[tc * RNN_H + r_own] = val;       // ds_write: staged output
    }
    barrier_lgkm();                         // NO vmcnt drain (R17 change)
    xv_cur = xv_next;
  };

  for (int c = 0; c < NCH; ++c) {
    // Phase A: commit prefetched chunk c to LDS; issue prefetch of c+1
    // (stays in flight across the lgkm-only barriers below); flush c-1.
    xb4[tid] = p0; xb4[tid + 512] = p1;
    if (c + 1 < NCH) {
      const float4* nx = xw4 + (long)(c + 1) * 1024;
      p0 = nx[tid]; p1 = nx[tid + 512];
    }
    if (c > 0) {
      out4[(long)(c - 1) * 1024 + tid]       = ob4[tid];
      out4[(long)(c - 1) * 1024 + tid + 512] = ob4[tid + 512];
    }
    barrier_lgkm();

    // Phase B: 32 steps, LDS-only traffic, compile-time h ping-pong.
    xv_cur = xbuf[r_own];  // tc = 0 of this chunk
    for (int tc = 0; tc < CH; tc += 2) {
      step(hbuf0, hbuf1, tc);
      step(hbuf1, hbuf0, tc + 1);
    }
  }

  // Final chunk flush + h_last (last step's barrier makes data visible)
  out4[(long)(NCH - 1) * 1024 + tid]       = ob4[tid];
  out4[(long)(NCH - 1) * 1024 + tid + 512] = ob4[tid + 512];
  if (tid < RNN_H)
    hlast[b * RNN_H + tid] = hbuf0[(tid >> 4) * 20 + (tid & 15)];
}

extern "C" void kernel_launch(void* const* d_in, const int* in_sizes, int n_in,
                              void* d_out, int out_size, void* d_ws, size_t ws_size,
                              hipStream_t stream) {
  const float* x    = (const float*)d_in[0];
  const float* h0   = (const float*)d_in[1];
  const float* W    = (const float*)d_in[2];
  const float* U    = (const float*)d_in[3];
  const float* b_ih = (const float*)d_in[4];
  const float* b_hh = (const float*)d_in[5];

  float* out   = (float*)d_out;                           // [B,T,H]
  float* hlast = out + (long)RNN_B * RNN_T * RNN_H;       // [B,H]

  // Stage 1: xw into the output region (read-before-write in scan, per chunk)
  rnn_xw_gemm<<<(RNN_B * RNN_T) / 64, 256, 0, stream>>>(x, W, b_ih, b_hh, out);
  // Stage 2: sequential recurrence, one block per batch element
  rnn_scan<<<RNN_B, 512, 0, stream>>>(out, out, hlast, h0, U);
}